// Round 1
// baseline (415.738 us; speedup 1.0000x reference)
//
#include <hip/hip_runtime.h>

#define NPTS 1048576
#define NCH 32
#define GS 96
#define GV (GS * GS * GS)
#define DIN 68
#define HD 128
#define TILE_PTS 48
#define NTILES ((NPTS + TILE_PTS - 1) / TILE_PTS)

typedef __bf16 bf16x8 __attribute__((ext_vector_type(8)));
typedef float f32x4 __attribute__((ext_vector_type(4)));

__device__ __forceinline__ unsigned int f2bf(float f) {
  unsigned int u = __float_as_uint(f);
  return (u + 0x7fffu + ((u >> 16) & 1u)) >> 16;  // RNE
}
__device__ __forceinline__ unsigned int pkbf(float a, float b) {
  return f2bf(a) | (f2bf(b) << 16);
}

// ---------------- grid transpose: [32][96^3] f32 -> [96^3][32] bf16 ----------------
__global__ __launch_bounds__(256) void k_prep_grid(const float* __restrict__ src,
                                                   unsigned int* __restrict__ dst) {
  __shared__ unsigned int tile[64 * 17];  // 64 voxels x 16 ch-pairs, pad 17
  const int tid = threadIdx.x;
  const long vb = (long)blockIdx.x * 64;
#pragma unroll
  for (int r = 0; r < 4; ++r) {
    int idx = r * 256 + tid;
    int c2 = idx >> 6;   // channel pair 0..15
    int dv = idx & 63;   // voxel in tile
    float f0 = src[(long)(2 * c2) * GV + vb + dv];
    float f1 = src[(long)(2 * c2 + 1) * GV + vb + dv];
    tile[dv * 17 + c2] = pkbf(f0, f1);
  }
  __syncthreads();
#pragma unroll
  for (int r = 0; r < 4; ++r) {
    int u = r * 256 + tid;
    int dv = u >> 4;
    int c2 = u & 15;
    dst[(vb + dv) * 16 + c2] = tile[dv * 17 + c2];
  }
}

// ---------------- fused main kernel ----------------
// LDS layout (bytes):
//   [0, 24576)        B0 fragments: 24 frags (kt*8+nt) * 1024   (layer0 W0^T, K pad 96)
//   [24576, 57344)    B1 fragments: 32 frags (kt*8+nt) * 1024   (layer1 W1^T)
//   [57344, 57856)    b0 (f32 x128)
//   [57856, 58368)    b1 (f32 x128)
//   [58368, 58880)    w2 (f32 x128)
//   [58880, 157184)   per-wave scratch 12288 B x 8 waves (A0 frags then h0 frags)
template <bool TA>
__global__ __launch_bounds__(512, 2) void k_fvsrn(
    const float* __restrict__ X, const float* __restrict__ gridF,
    const unsigned short* __restrict__ gridT,
    const float* __restrict__ W0, const float* __restrict__ B0,
    const float* __restrict__ W1, const float* __restrict__ B1,
    const float* __restrict__ W2, const float* __restrict__ B2,
    float* __restrict__ out, int ntiles) {
  extern __shared__ char smem[];
  float* lb0 = (float*)(smem + 57344);
  float* lb1 = (float*)(smem + 57856);
  float* lw2 = (float*)(smem + 58368);
  const int tid = threadIdx.x;

  // --- build weight B-fragments in LDS (B[k][n]: lane holds n=lane&15, k=(lane>>4)*8+j)
  for (int idx = tid; idx < 56 * 64; idx += 512) {
    int f = idx >> 6;
    int L = idx & 63;
    int qq = L >> 4, lnn = L & 15;
    float vals[8];
    if (f < 24) {
      int kt = f >> 3, nt = f & 7;
      int n = nt * 16 + lnn;
      int kb = kt * 32 + qq * 8;
#pragma unroll
      for (int j = 0; j < 8; ++j) {
        int k = kb + j;
        vals[j] = (k < DIN) ? W0[n * DIN + k] : 0.f;
      }
    } else {
      int g = f - 24;
      int kt = g >> 3, nt = g & 7;
      int n = nt * 16 + lnn;
      int kb = kt * 32 + qq * 8;
#pragma unroll
      for (int j = 0; j < 8; ++j) vals[j] = W1[n * HD + kb + j];
    }
    uint4 pk;
    pk.x = pkbf(vals[0], vals[1]);
    pk.y = pkbf(vals[2], vals[3]);
    pk.z = pkbf(vals[4], vals[5]);
    pk.w = pkbf(vals[6], vals[7]);
    *(uint4*)(smem + f * 1024 + L * 16) = pk;
  }
  if (tid < 128) lb0[tid] = B0[tid];
  else if (tid < 256) lb1[tid - 128] = B1[tid - 128];
  else if (tid < 384) lw2[tid - 256] = W2[tid - 256];
  __syncthreads();

  const int wave = tid >> 6, lane = tid & 63;
  const int tileId = blockIdx.x * 8 + wave;
  if (tileId >= ntiles) return;  // no barriers beyond this point
  const long p0 = (long)tileId * TILE_PTS;
  char* scr = smem + 58880 + wave * 12288;
  const int q = lane >> 4, ln = lane & 15;

  // ---- phase G: gather + posenc, write A0 fragment-linear (lanes 0..47, 1 pt/lane)
  if (lane < 48) {
    long p = p0 + lane;
    if (p >= NPTS) p = NPTS - 1;  // tail clamp; stores are guarded later
    float px = X[p * 3 + 0], py = X[p * 3 + 1], pz = X[p * 3 + 2];
    float v[96];
    float fr = 3.14159265358979f;
#pragma unroll
    for (int i = 0; i < 6; ++i) {
      float s, c;
      __sincosf(px * fr, &s, &c);
      v[i * 6 + 0] = s; v[i * 6 + 3] = c;
      __sincosf(py * fr, &s, &c);
      v[i * 6 + 1] = s; v[i * 6 + 4] = c;
      __sincosf(pz * fr, &s, &c);
      v[i * 6 + 2] = s; v[i * 6 + 5] = c;
      fr *= 2.f;
    }
#pragma unroll
    for (int k = 36; k < 96; ++k) v[k] = 0.f;

    float fx = (px + 1.f) * 0.5f * (GS - 1);
    float fy = (py + 1.f) * 0.5f * (GS - 1);
    float fz = (pz + 1.f) * 0.5f * (GS - 1);
    float flx = floorf(fx), fly = floorf(fy), flz = floorf(fz);
    float wx = fx - flx, wy = fy - fly, wz = fz - flz;
    int jx = (int)flx, jy = (int)fly, jz = (int)flz;
    int ixa0 = min(max(jx, 0), GS - 1), ixa1 = min(max(jx + 1, 0), GS - 1);
    int iya0 = min(max(jy, 0), GS - 1), iya1 = min(max(jy + 1, 0), GS - 1);
    int iza0 = min(max(jz, 0), GS - 1), iza1 = min(max(jz + 1, 0), GS - 1);

#pragma unroll
    for (int zi = 0; zi < 2; ++zi) {
      int izz = zi ? iza1 : iza0;
      float wzz = zi ? wz : 1.f - wz;
#pragma unroll
      for (int yi = 0; yi < 2; ++yi) {
        int iyy = yi ? iya1 : iya0;
        float wyy = yi ? wy : 1.f - wy;
#pragma unroll
        for (int xi = 0; xi < 2; ++xi) {
          int ixx = xi ? ixa1 : ixa0;
          float w = wzz * wyy * (xi ? wx : 1.f - wx);
          long vi = ((long)izz * GS + iyy) * GS + ixx;
          if constexpr (TA) {
            const uint4* gp = (const uint4*)(gridT + vi * NCH);
            uint4 g0 = gp[0], g1 = gp[1], g2 = gp[2], g3 = gp[3];
#define ACC_PAIR(u, b)                                  \
  v[b] += w * __uint_as_float((u) << 16);               \
  v[(b) + 1] += w * __uint_as_float((u) & 0xffff0000u);
            ACC_PAIR(g0.x, 36) ACC_PAIR(g0.y, 38) ACC_PAIR(g0.z, 40) ACC_PAIR(g0.w, 42)
            ACC_PAIR(g1.x, 44) ACC_PAIR(g1.y, 46) ACC_PAIR(g1.z, 48) ACC_PAIR(g1.w, 50)
            ACC_PAIR(g2.x, 52) ACC_PAIR(g2.y, 54) ACC_PAIR(g2.z, 56) ACC_PAIR(g2.w, 58)
            ACC_PAIR(g3.x, 60) ACC_PAIR(g3.y, 62) ACC_PAIR(g3.z, 64) ACC_PAIR(g3.w, 66)
#undef ACC_PAIR
          } else {
#pragma unroll
            for (int c = 0; c < NCH; ++c)
              v[36 + c] += w * gridF[(long)c * GV + vi];
          }
        }
      }
    }
    // A0 fragment-linear write: A[m=lane&15][k=(lane>>4)*8+j], frag = mt*3+kt
    int mt = lane >> 4, pm = lane & 15;
#pragma unroll
    for (int kt = 0; kt < 3; ++kt)
#pragma unroll
      for (int qq = 0; qq < 4; ++qq) {
        int kb = kt * 32 + qq * 8;
        uint4 pk;
        pk.x = pkbf(v[kb + 0], v[kb + 1]);
        pk.y = pkbf(v[kb + 2], v[kb + 3]);
        pk.z = pkbf(v[kb + 4], v[kb + 5]);
        pk.w = pkbf(v[kb + 6], v[kb + 7]);
        *(uint4*)(scr + (mt * 3 + kt) * 1024 + (qq * 16 + pm) * 16) = pk;
      }
  }
  __builtin_amdgcn_wave_barrier();  // wave-private LDS: DS pipe is in-order per wave

  // ---- layer 0: h0 = relu(A0 * W0^T + b0)
  bf16x8 a0[9];
#pragma unroll
  for (int mt = 0; mt < 3; ++mt)
#pragma unroll
    for (int kt = 0; kt < 3; ++kt)
      a0[mt * 3 + kt] = *(const bf16x8*)(scr + (mt * 3 + kt) * 1024 + lane * 16);
  __builtin_amdgcn_wave_barrier();
#pragma unroll
  for (int nt = 0; nt < 8; ++nt) {
    float bn = lb0[nt * 16 + ln];
    f32x4 cinit = {bn, bn, bn, bn};
    f32x4 acc[3];
#pragma unroll
    for (int mt = 0; mt < 3; ++mt) acc[mt] = cinit;
#pragma unroll
    for (int kt = 0; kt < 3; ++kt) {
      bf16x8 bfr = *(const bf16x8*)(smem + (kt * 8 + nt) * 1024 + lane * 16);
#pragma unroll
      for (int mt = 0; mt < 3; ++mt)
        acc[mt] = __builtin_amdgcn_mfma_f32_16x16x32_bf16(a0[mt * 3 + kt], bfr, acc[mt], 0, 0, 0);
    }
    // epilogue: C-layout (col n=lane&15, row m=(lane>>4)*4+r) -> A-frag-linear h0 in scr
    int n = nt * 16 + ln;
    int kt1 = n >> 5, j = n & 7, sub = (n >> 3) & 3;
#pragma unroll
    for (int mt = 0; mt < 3; ++mt)
#pragma unroll
      for (int r = 0; r < 4; ++r) {
        float h = fmaxf(acc[mt][r], 0.f);
        *(unsigned short*)(scr + (mt * 4 + kt1) * 1024 + (sub * 16 + q * 4 + r) * 16 + j * 2) =
            (unsigned short)f2bf(h);
      }
  }
  __builtin_amdgcn_wave_barrier();

  // ---- layer 1 + fused layer 2
  bf16x8 a1[12];
#pragma unroll
  for (int mt = 0; mt < 3; ++mt)
#pragma unroll
    for (int kt = 0; kt < 4; ++kt)
      a1[mt * 4 + kt] = *(const bf16x8*)(scr + (mt * 4 + kt) * 1024 + lane * 16);
  float y[12];
#pragma unroll
  for (int i = 0; i < 12; ++i) y[i] = 0.f;
#pragma unroll
  for (int nt = 0; nt < 8; ++nt) {
    float bn = lb1[nt * 16 + ln];
    float w2n = lw2[nt * 16 + ln];
    f32x4 cinit = {bn, bn, bn, bn};
    f32x4 acc[3];
#pragma unroll
    for (int mt = 0; mt < 3; ++mt) acc[mt] = cinit;
#pragma unroll
    for (int kt = 0; kt < 4; ++kt) {
      bf16x8 bfr = *(const bf16x8*)(smem + 24576 + (kt * 8 + nt) * 1024 + lane * 16);
#pragma unroll
      for (int mt = 0; mt < 3; ++mt)
        acc[mt] = __builtin_amdgcn_mfma_f32_16x16x32_bf16(a1[mt * 4 + kt], bfr, acc[mt], 0, 0, 0);
    }
#pragma unroll
    for (int mt = 0; mt < 3; ++mt)
#pragma unroll
      for (int r = 0; r < 4; ++r)
        y[mt * 4 + r] += w2n * fmaxf(acc[mt][r], 0.f);  // layer2 partial, fp32
  }
  float b2s = B2[0];
#pragma unroll
  for (int i = 0; i < 12; ++i) {
    float t = y[i];
    t += __shfl_xor(t, 1);
    t += __shfl_xor(t, 2);
    t += __shfl_xor(t, 4);
    t += __shfl_xor(t, 8);
    y[i] = t;
  }
  if (ln == 0) {
#pragma unroll
    for (int mt = 0; mt < 3; ++mt)
#pragma unroll
      for (int r = 0; r < 4; ++r) {
        long m = p0 + mt * 16 + q * 4 + r;
        if (m < NPTS) out[m] = (y[mt * 4 + r] + b2s) * 2.f - 1.f;  // *(VMAX-VMIN)+VMIN
      }
  }
}

extern "C" void kernel_launch(void* const* d_in, const int* in_sizes, int n_in,
                              void* d_out, int out_size, void* d_ws, size_t ws_size,
                              hipStream_t stream) {
  const float* X  = (const float*)d_in[0];
  const float* G  = (const float*)d_in[1];
  const float* W0 = (const float*)d_in[2];
  const float* B0 = (const float*)d_in[3];
  const float* W1 = (const float*)d_in[4];
  const float* B1 = (const float*)d_in[5];
  const float* W2 = (const float*)d_in[6];
  const float* B2 = (const float*)d_in[7];
  float* out = (float*)d_out;

  const size_t needT = (size_t)GV * NCH * 2;  // 56,623,104 B transposed bf16 grid
  const int ntiles = NTILES;                  // 21846
  const int nblocks = (ntiles + 7) / 8;       // 2731
  const size_t shmem = 157184;

  if (ws_size >= needT) {
    k_prep_grid<<<GV / 64, 256, 0, stream>>>(G, (unsigned int*)d_ws);
    k_fvsrn<true><<<nblocks, 512, shmem, stream>>>(
        X, G, (const unsigned short*)d_ws, W0, B0, W1, B1, W2, B2, out, ntiles);
  } else {
    k_fvsrn<false><<<nblocks, 512, shmem, stream>>>(
        X, G, (const unsigned short*)nullptr, W0, B0, W1, B1, W2, B2, out, ntiles);
  }
}

// Round 2
// 329.774 us; speedup vs baseline: 1.2607x; 1.2607x over previous
//
#include <hip/hip_runtime.h>

#define NPTS 1048576
#define NCH 32
#define GS 96
#define GV (GS * GS * GS)
#define DIN 68
#define HD 128
#define TILE_PTS 48
#define NTILES ((NPTS + TILE_PTS - 1) / TILE_PTS)
#define NBLK 256
#define WAVES_TOT (NBLK * 8)

typedef __bf16 bf16x8 __attribute__((ext_vector_type(8)));
typedef float f32x4 __attribute__((ext_vector_type(4)));

__device__ __forceinline__ unsigned int f2bf(float f) {
  unsigned int u = __float_as_uint(f);
  return (u + 0x7fffu + ((u >> 16) & 1u)) >> 16;  // RNE
}
__device__ __forceinline__ unsigned int pkbf(float a, float b) {
  return f2bf(a) | (f2bf(b) << 16);
}

// ---------------- grid transpose: [32][96^3] f32 -> [96^3][32] bf16 ----------------
// 256 voxels/block, float4 loads (16B/lane), uint4 stores (16B/lane).
__global__ __launch_bounds__(256) void k_prep_grid(const float* __restrict__ src,
                                                   unsigned int* __restrict__ dst) {
  __shared__ unsigned int tile[256 * 17];  // [vox][c2-pair], stride 17 kills conflicts
  const int tid = threadIdx.x;
  const long vb = (long)blockIdx.x * 256;
  const int c2 = tid >> 4;       // channel pair 0..15
  const int vgb = tid & 15;      // voxel group
#pragma unroll
  for (int p = 0; p < 4; ++p) {
    int vox = (vgb + p * 16) * 4;
    const float4 a = *(const float4*)(src + (long)(2 * c2) * GV + vb + vox);
    const float4 b = *(const float4*)(src + (long)(2 * c2 + 1) * GV + vb + vox);
    tile[(vox + 0) * 17 + c2] = pkbf(a.x, b.x);
    tile[(vox + 1) * 17 + c2] = pkbf(a.y, b.y);
    tile[(vox + 2) * 17 + c2] = pkbf(a.z, b.z);
    tile[(vox + 3) * 17 + c2] = pkbf(a.w, b.w);
  }
  __syncthreads();
  const int vox2 = tid >> 2;
  const int c4 = (tid & 3) * 4;
#pragma unroll
  for (int j = 0; j < 4; ++j) {
    int vx = vox2 + j * 64;
    uint4 w;
    w.x = tile[vx * 17 + c4 + 0];
    w.y = tile[vx * 17 + c4 + 1];
    w.z = tile[vx * 17 + c4 + 2];
    w.w = tile[vx * 17 + c4 + 3];
    *(uint4*)(dst + (vb + vx) * 16 + c4) = w;  // lane-contiguous 16B -> coalesced
  }
}

// ---------------- fused main kernel ----------------
// LDS layout (bytes):
//   [0, 24576)        B0 fragments: 24 frags (kt*8+nt) * 1024   (layer0 W0^T, K pad 96)
//   [24576, 57344)    B1 fragments: 32 frags (kt*8+nt) * 1024   (layer1 W1^T)
//   [57344, 57856)    b0 (f32 x128)
//   [57856, 58368)    b1 (f32 x128)
//   [58368, 58880)    w2 (f32 x128)
//   [58880, 157184)   per-wave scratch 12288 B x 8 waves (A0 frags then h0 frags)
template <bool TA>
__global__ __launch_bounds__(512, 2) void k_fvsrn(
    const float* __restrict__ X, const float* __restrict__ gridF,
    const unsigned short* __restrict__ gridT,
    const float* __restrict__ W0, const float* __restrict__ B0,
    const float* __restrict__ W1, const float* __restrict__ B1,
    const float* __restrict__ W2, const float* __restrict__ B2,
    float* __restrict__ out, int ntiles) {
  extern __shared__ char smem[];
  float* lb0 = (float*)(smem + 57344);
  float* lb1 = (float*)(smem + 57856);
  float* lw2 = (float*)(smem + 58368);
  const int tid = threadIdx.x;

  // --- build weight B-fragments in LDS, once per block (256 blocks total)
  for (int idx = tid; idx < 56 * 64; idx += 512) {
    int f = idx >> 6;
    int L = idx & 63;
    int qq = L >> 4, lnn = L & 15;
    float vals[8];
    if (f < 24) {
      int kt = f >> 3, nt = f & 7;
      int n = nt * 16 + lnn;
      int kb = kt * 32 + qq * 8;
#pragma unroll
      for (int j = 0; j < 8; ++j) {
        int k = kb + j;
        vals[j] = (k < DIN) ? W0[n * DIN + k] : 0.f;
      }
    } else {
      int g = f - 24;
      int kt = g >> 3, nt = g & 7;
      int n = nt * 16 + lnn;
      int kb = kt * 32 + qq * 8;
#pragma unroll
      for (int j = 0; j < 8; ++j) vals[j] = W1[n * HD + kb + j];
    }
    uint4 pk;
    pk.x = pkbf(vals[0], vals[1]);
    pk.y = pkbf(vals[2], vals[3]);
    pk.z = pkbf(vals[4], vals[5]);
    pk.w = pkbf(vals[6], vals[7]);
    *(uint4*)(smem + f * 1024 + L * 16) = pk;
  }
  if (tid < 128) lb0[tid] = B0[tid];
  else if (tid < 256) lb1[tid - 128] = B1[tid - 128];
  else if (tid < 384) lw2[tid - 256] = W2[tid - 256];
  __syncthreads();

  const int wave = tid >> 6, lane = tid & 63;
  char* scr = smem + 58880 + wave * 12288;
  const int q = lane >> 4, ln = lane & 15;
  const int mt0 = lane >> 4, pm = lane & 15;  // gather lane mapping (lane<48)
  const float b2s = B2[0];

  int t = blockIdx.x * 8 + wave;
  // prefetch X for first tile
  float px = 0.f, py = 0.f, pz = 0.f;
  if (t < ntiles && lane < 48) {
    long p = t * (long)TILE_PTS + lane;
    if (p >= NPTS) p = NPTS - 1;
    px = X[p * 3 + 0]; py = X[p * 3 + 1]; pz = X[p * 3 + 2];
  }

  for (; t < ntiles;) {
    const int tn = t + WAVES_TOT;
    const long p0 = (long)t * TILE_PTS;

    // ---- phase G: posenc + gather -> 48 packed dwords (registers only)
    unsigned int dwall[48];
    if (lane < 48) {
      // posenc via sincos ladder: sin/cos(pi*2^i*x) from one __sincosf per axis
      float v36[36];
      {
        const float PIf = 3.14159265358979f;
        float cc[3] = {px, py, pz};
#pragma unroll
        for (int ax = 0; ax < 3; ++ax) {
          float s, co;
          __sincosf(PIf * cc[ax], &s, &co);
#pragma unroll
          for (int i = 0; i < 6; ++i) {
            v36[i * 6 + ax] = s;
            v36[i * 6 + 3 + ax] = co;
            float s2 = 2.f * s * co;   // sin(2a) = 2 sin cos
            co = 1.f - 2.f * s * s;    // cos(2a) = 1 - 2 sin^2
            s = s2;
          }
        }
      }
#pragma unroll
      for (int d = 0; d < 18; ++d) dwall[d] = pkbf(v36[2 * d], v36[2 * d + 1]);

      // trilinear gather, fp32 accumulation in 32 regs
      float fx = (px + 1.f) * 0.5f * (GS - 1);
      float fy = (py + 1.f) * 0.5f * (GS - 1);
      float fz = (pz + 1.f) * 0.5f * (GS - 1);
      float flx = floorf(fx), fly = floorf(fy), flz = floorf(fz);
      float wx = fx - flx, wy = fy - fly, wz = fz - flz;
      int jx = (int)flx, jy = (int)fly, jz = (int)flz;
      int ixa0 = min(max(jx, 0), GS - 1), ixa1 = min(max(jx + 1, 0), GS - 1);
      int iya0 = min(max(jy, 0), GS - 1), iya1 = min(max(jy + 1, 0), GS - 1);
      int iza0 = min(max(jz, 0), GS - 1), iza1 = min(max(jz + 1, 0), GS - 1);

      float feat[32];
#pragma unroll
      for (int c = 0; c < 32; ++c) feat[c] = 0.f;

#pragma unroll
      for (int zi = 0; zi < 2; ++zi) {
        int izz = zi ? iza1 : iza0;
        float wzz = zi ? wz : 1.f - wz;
#pragma unroll
        for (int yi = 0; yi < 2; ++yi) {
          int iyy = yi ? iya1 : iya0;
          float wyy = yi ? wy : 1.f - wy;
#pragma unroll
          for (int xi = 0; xi < 2; ++xi) {
            int ixx = xi ? ixa1 : ixa0;
            float w = wzz * wyy * (xi ? wx : 1.f - wx);
            long vi = ((long)izz * GS + iyy) * GS + ixx;
            if constexpr (TA) {
              const uint4* gp = (const uint4*)(gridT + vi * NCH);
              uint4 g0 = gp[0], g1 = gp[1], g2 = gp[2], g3 = gp[3];
#define ACC_PAIR(u, b)                                      \
  feat[b] += w * __uint_as_float((u) << 16);                \
  feat[(b) + 1] += w * __uint_as_float((u) & 0xffff0000u);
              ACC_PAIR(g0.x, 0)  ACC_PAIR(g0.y, 2)  ACC_PAIR(g0.z, 4)  ACC_PAIR(g0.w, 6)
              ACC_PAIR(g1.x, 8)  ACC_PAIR(g1.y, 10) ACC_PAIR(g1.z, 12) ACC_PAIR(g1.w, 14)
              ACC_PAIR(g2.x, 16) ACC_PAIR(g2.y, 18) ACC_PAIR(g2.z, 20) ACC_PAIR(g2.w, 22)
              ACC_PAIR(g3.x, 24) ACC_PAIR(g3.y, 26) ACC_PAIR(g3.z, 28) ACC_PAIR(g3.w, 30)
#undef ACC_PAIR
            } else {
#pragma unroll
              for (int c = 0; c < NCH; ++c)
                feat[c] += w * gridF[(long)c * GV + vi];
            }
          }
        }
      }
#pragma unroll
      for (int d = 0; d < 16; ++d) dwall[18 + d] = pkbf(feat[2 * d], feat[2 * d + 1]);
#pragma unroll
      for (int d = 34; d < 48; ++d) dwall[d] = 0u;

      // A0 fragment-linear write: A[m=lane&15][k=(lane>>4)*8+j], frag = mt*3+kt
#pragma unroll
      for (int kt = 0; kt < 3; ++kt)
#pragma unroll
        for (int qq = 0; qq < 4; ++qq) {
          int b = kt * 16 + qq * 4;
          uint4 pk;
          pk.x = dwall[b + 0]; pk.y = dwall[b + 1];
          pk.z = dwall[b + 2]; pk.w = dwall[b + 3];
          *(uint4*)(scr + (mt0 * 3 + kt) * 1024 + (qq * 16 + pm) * 16) = pk;
        }
    }
    __builtin_amdgcn_wave_barrier();  // wave-private LDS; DS pipe is in-order per wave

    // prefetch next tile's coords while MFMA phases run
    if (tn < ntiles && lane < 48) {
      long p = tn * (long)TILE_PTS + lane;
      if (p >= NPTS) p = NPTS - 1;
      px = X[p * 3 + 0]; py = X[p * 3 + 1]; pz = X[p * 3 + 2];
    }

    // ---- layer 0: h0 = relu(A0 * W0^T + b0)
    bf16x8 a0[9];
#pragma unroll
    for (int mt = 0; mt < 3; ++mt)
#pragma unroll
      for (int kt = 0; kt < 3; ++kt)
        a0[mt * 3 + kt] = *(const bf16x8*)(scr + (mt * 3 + kt) * 1024 + lane * 16);
    __builtin_amdgcn_wave_barrier();
#pragma unroll
    for (int nt = 0; nt < 8; ++nt) {
      float bn = lb0[nt * 16 + ln];
      f32x4 cinit = {bn, bn, bn, bn};
      f32x4 acc[3];
#pragma unroll
      for (int mt = 0; mt < 3; ++mt) acc[mt] = cinit;
#pragma unroll
      for (int kt = 0; kt < 3; ++kt) {
        bf16x8 bfr = *(const bf16x8*)(smem + (kt * 8 + nt) * 1024 + lane * 16);
#pragma unroll
        for (int mt = 0; mt < 3; ++mt)
          acc[mt] = __builtin_amdgcn_mfma_f32_16x16x32_bf16(a0[mt * 3 + kt], bfr, acc[mt], 0, 0, 0);
      }
      // epilogue: C-layout (col n=lane&15, row m=(lane>>4)*4+r) -> A-frag-linear h0
      int n = nt * 16 + ln;
      int kt1 = n >> 5, j = n & 7, sub = (n >> 3) & 3;
#pragma unroll
      for (int mt = 0; mt < 3; ++mt)
#pragma unroll
        for (int r = 0; r < 4; ++r) {
          float h = fmaxf(acc[mt][r], 0.f);
          *(unsigned short*)(scr + (mt * 4 + kt1) * 1024 + (sub * 16 + q * 4 + r) * 16 + j * 2) =
              (unsigned short)f2bf(h);
        }
    }
    __builtin_amdgcn_wave_barrier();

    // ---- layer 1 + fused layer 2
    bf16x8 a1[12];
#pragma unroll
    for (int mt = 0; mt < 3; ++mt)
#pragma unroll
      for (int kt = 0; kt < 4; ++kt)
        a1[mt * 4 + kt] = *(const bf16x8*)(scr + (mt * 4 + kt) * 1024 + lane * 16);
    __builtin_amdgcn_wave_barrier();
    float y[12];
#pragma unroll
    for (int i = 0; i < 12; ++i) y[i] = 0.f;
#pragma unroll
    for (int nt = 0; nt < 8; ++nt) {
      float bn = lb1[nt * 16 + ln];
      float w2n = lw2[nt * 16 + ln];
      f32x4 cinit = {bn, bn, bn, bn};
      f32x4 acc[3];
#pragma unroll
      for (int mt = 0; mt < 3; ++mt) acc[mt] = cinit;
#pragma unroll
      for (int kt = 0; kt < 4; ++kt) {
        bf16x8 bfr = *(const bf16x8*)(smem + 24576 + (kt * 8 + nt) * 1024 + lane * 16);
#pragma unroll
        for (int mt = 0; mt < 3; ++mt)
          acc[mt] = __builtin_amdgcn_mfma_f32_16x16x32_bf16(a1[mt * 4 + kt], bfr, acc[mt], 0, 0, 0);
      }
#pragma unroll
      for (int mt = 0; mt < 3; ++mt)
#pragma unroll
        for (int r = 0; r < 4; ++r)
          y[mt * 4 + r] += w2n * fmaxf(acc[mt][r], 0.f);  // layer2 partial, fp32
    }
#pragma unroll
    for (int i = 0; i < 12; ++i) {
      float v = y[i];
      v += __shfl_xor(v, 1);
      v += __shfl_xor(v, 2);
      v += __shfl_xor(v, 4);
      v += __shfl_xor(v, 8);
      y[i] = v;
    }
    if (ln == 0) {
#pragma unroll
      for (int mt = 0; mt < 3; ++mt)
#pragma unroll
        for (int r = 0; r < 4; ++r) {
          long m = p0 + mt * 16 + q * 4 + r;
          if (m < NPTS) out[m] = (y[mt * 4 + r] + b2s) * 2.f - 1.f;  // *(VMAX-VMIN)+VMIN
        }
    }
    t = tn;
  }
}

extern "C" void kernel_launch(void* const* d_in, const int* in_sizes, int n_in,
                              void* d_out, int out_size, void* d_ws, size_t ws_size,
                              hipStream_t stream) {
  const float* X  = (const float*)d_in[0];
  const float* G  = (const float*)d_in[1];
  const float* W0 = (const float*)d_in[2];
  const float* B0 = (const float*)d_in[3];
  const float* W1 = (const float*)d_in[4];
  const float* B1 = (const float*)d_in[5];
  const float* W2 = (const float*)d_in[6];
  const float* B2 = (const float*)d_in[7];
  float* out = (float*)d_out;

  const size_t needT = (size_t)GV * NCH * 2;  // 56,623,104 B transposed bf16 grid
  const int ntiles = NTILES;                  // 21846
  const size_t shmem = 157184;

  if (ws_size >= needT) {
    k_prep_grid<<<GV / 256, 256, 0, stream>>>(G, (unsigned int*)d_ws);
    k_fvsrn<true><<<NBLK, 512, shmem, stream>>>(
        X, G, (const unsigned short*)d_ws, W0, B0, W1, B1, W2, B2, out, ntiles);
  } else {
    k_fvsrn<false><<<NBLK, 512, shmem, stream>>>(
        X, G, (const unsigned short*)nullptr, W0, B0, W1, B1, W2, B2, out, ntiles);
  }
}

// Round 3
// 300.993 us; speedup vs baseline: 1.3812x; 1.0956x over previous
//
#include <hip/hip_runtime.h>

#define NPTS 1048576
#define NCH 32
#define GS 96
#define GV (GS * GS * GS)
#define DIN 68
#define HD 128
#define TILE_PTS 32
#define NTILES (NPTS / TILE_PTS)   // 32768 exact, no tail
#define NBLK 256
#define NTHR 768                   // 12 waves/block, 1 block/CU -> 3 waves/SIMD
#define WAVES_TOT (NBLK * 12)

typedef __bf16 bf16x8 __attribute__((ext_vector_type(8)));
typedef float f32x4 __attribute__((ext_vector_type(4)));
typedef float f32x2 __attribute__((ext_vector_type(2)));

__device__ __forceinline__ unsigned int f2bf(float f) {
  unsigned int u = __float_as_uint(f);
  return (u + 0x7fffu + ((u >> 16) & 1u)) >> 16;  // RNE
}
__device__ __forceinline__ unsigned int pkbf(float a, float b) {
  return f2bf(a) | (f2bf(b) << 16);
}

// ---------------- grid transpose: [32][96^3] f32 -> [96^3][32] bf16 ----------------
__global__ __launch_bounds__(256) void k_prep_grid(const float* __restrict__ src,
                                                   unsigned int* __restrict__ dst) {
  __shared__ unsigned int tile[256 * 17];
  const int tid = threadIdx.x;
  const long vb = (long)blockIdx.x * 256;
  const int c2 = tid >> 4;
  const int vgb = tid & 15;
#pragma unroll
  for (int p = 0; p < 4; ++p) {
    int vox = (vgb + p * 16) * 4;
    const float4 a = *(const float4*)(src + (long)(2 * c2) * GV + vb + vox);
    const float4 b = *(const float4*)(src + (long)(2 * c2 + 1) * GV + vb + vox);
    tile[(vox + 0) * 17 + c2] = pkbf(a.x, b.x);
    tile[(vox + 1) * 17 + c2] = pkbf(a.y, b.y);
    tile[(vox + 2) * 17 + c2] = pkbf(a.z, b.z);
    tile[(vox + 3) * 17 + c2] = pkbf(a.w, b.w);
  }
  __syncthreads();
  const int vox2 = tid >> 2;
  const int c4 = (tid & 3) * 4;
#pragma unroll
  for (int j = 0; j < 4; ++j) {
    int vx = vox2 + j * 64;
    uint4 w;
    w.x = tile[vx * 17 + c4 + 0];
    w.y = tile[vx * 17 + c4 + 1];
    w.z = tile[vx * 17 + c4 + 2];
    w.w = tile[vx * 17 + c4 + 3];
    *(uint4*)(dst + (vb + vx) * 16 + c4) = w;
  }
}

// ---------------- fused main kernel ----------------
// K-order is REORDERED: k=0..31 -> grid feats ch k (W0 col 36+k); k=32..67 -> posenc dim k-32.
// LDS layout (bytes):
//   [0, 24576)        B0 frags: 24 (kt*8+nt) * 1024
//   [24576, 57344)    B1 frags: 32 (kt*8+nt) * 1024
//   [57344, 58880)    b0 / b1 / w2 (f32 x128 each)
//   [58880, 157184)   per-wave scratch 8192 B x 12 waves (A0 frags 0..5, h0 frags 0..7 overlap)
template <bool TA>
__global__ __launch_bounds__(NTHR, 3) void k_fvsrn(
    const float* __restrict__ X, const float* __restrict__ gridF,
    const unsigned short* __restrict__ gridT,
    const float* __restrict__ W0, const float* __restrict__ B0,
    const float* __restrict__ W1, const float* __restrict__ B1,
    const float* __restrict__ W2, const float* __restrict__ B2,
    float* __restrict__ out) {
  extern __shared__ char smem[];
  float* lb0 = (float*)(smem + 57344);
  float* lb1 = (float*)(smem + 57856);
  float* lw2 = (float*)(smem + 58368);
  const int tid = threadIdx.x;

  // --- build weight B-fragments in LDS (once per block; 256 blocks)
  for (int idx = tid; idx < 56 * 64; idx += NTHR) {
    int f = idx >> 6;
    int L = idx & 63;
    int qq = L >> 4, lnn = L & 15;
    float vals[8];
    if (f < 24) {
      int kt = f >> 3, nt = f & 7;
      int n = nt * 16 + lnn;
      int kb = kt * 32 + qq * 8;
#pragma unroll
      for (int j = 0; j < 8; ++j) {
        int k = kb + j;
        float w = 0.f;
        if (k < 32) w = W0[n * DIN + 36 + k];        // feat cols
        else if (k < DIN) w = W0[n * DIN + (k - 32)]; // posenc cols
        vals[j] = w;
      }
    } else {
      int g = f - 24;
      int kt = g >> 3, nt = g & 7;
      int n = nt * 16 + lnn;
      int kb = kt * 32 + qq * 8;
#pragma unroll
      for (int j = 0; j < 8; ++j) vals[j] = W1[n * HD + kb + j];
    }
    uint4 pk;
    pk.x = pkbf(vals[0], vals[1]);
    pk.y = pkbf(vals[2], vals[3]);
    pk.z = pkbf(vals[4], vals[5]);
    pk.w = pkbf(vals[6], vals[7]);
    *(uint4*)(smem + f * 1024 + L * 16) = pk;
  }
  if (tid < 128) lb0[tid] = B0[tid];
  else if (tid < 256) lb1[tid - 128] = B1[tid - 128];
  else if (tid < 384) lw2[tid - 256] = W2[tid - 256];
  __syncthreads();

  const int wave = tid >> 6, lane = tid & 63;
  char* scr = smem + 58880 + wave * 8192;
  const int q = lane >> 4, ln = lane & 15;     // MFMA-phase roles
  const int half = lane >> 5, pt = lane & 31;  // gather-phase roles (2 lanes/pt)
  const int mtg = pt >> 4, pmg = pt & 15;
  const float b2s = B2[0];

  int t = blockIdx.x * 12 + wave;
  float px = 0.f, py = 0.f, pz = 0.f;
  if (t < NTILES) {
    long p = (long)t * TILE_PTS + pt;
    px = X[p * 3 + 0]; py = X[p * 3 + 1]; pz = X[p * 3 + 2];
  }

  for (; t < NTILES;) {
    const int tn = t + WAVES_TOT;
    const long p0 = (long)t * TILE_PTS;

    // ---- posenc ladder (full 36 dims per lane; 2x redundant across halves)
    float v36[36];
    {
      const float PIf = 3.14159265358979f;
      float cc[3] = {px, py, pz};
#pragma unroll
      for (int ax = 0; ax < 3; ++ax) {
        float s, co;
        __sincosf(PIf * cc[ax], &s, &co);
#pragma unroll
        for (int i = 0; i < 6; ++i) {
          v36[i * 6 + ax] = s;
          v36[i * 6 + 3 + ax] = co;
          float s2 = 2.f * s * co;
          co = 1.f - 2.f * s * s;
          s = s2;
        }
      }
    }
    // pack this lane's posenc slice: dims [16*half, 16*half+16) -> pd[0..7]; kt2 extras
    unsigned int pd[8], e0, e1;
    if (half == 0) {
#pragma unroll
      for (int d = 0; d < 8; ++d) pd[d] = pkbf(v36[2 * d], v36[2 * d + 1]);
      e0 = pkbf(v36[32], v36[33]);
      e1 = pkbf(v36[34], v36[35]);
    } else {
#pragma unroll
      for (int d = 0; d < 8; ++d) pd[d] = pkbf(v36[16 + 2 * d], v36[17 + 2 * d]);
      e0 = 0u; e1 = 0u;
    }

    // ---- trilinear gather: this lane accumulates channels [16*half, 16*half+16)
    f32x2 f2[8];
#pragma unroll
    for (int i = 0; i < 8; ++i) f2[i] = (f32x2){0.f, 0.f};
    {
      float fx = (px + 1.f) * 0.5f * (GS - 1);
      float fy = (py + 1.f) * 0.5f * (GS - 1);
      float fz = (pz + 1.f) * 0.5f * (GS - 1);
      float flx = floorf(fx), fly = floorf(fy), flz = floorf(fz);
      float wx = fx - flx, wy = fy - fly, wz = fz - flz;
      int jx = (int)flx, jy = (int)fly, jz = (int)flz;
      int ixa0 = min(max(jx, 0), GS - 1), ixa1 = min(max(jx + 1, 0), GS - 1);
      int iya0 = min(max(jy, 0), GS - 1), iya1 = min(max(jy + 1, 0), GS - 1);
      int iza0 = min(max(jz, 0), GS - 1), iza1 = min(max(jz + 1, 0), GS - 1);
#pragma unroll
      for (int zi = 0; zi < 2; ++zi) {
        int izz = zi ? iza1 : iza0;
        float wzz = zi ? wz : 1.f - wz;
#pragma unroll
        for (int yi = 0; yi < 2; ++yi) {
          int iyy = yi ? iya1 : iya0;
          float wyy = yi ? wy : 1.f - wy;
#pragma unroll
          for (int xi = 0; xi < 2; ++xi) {
            int ixx = xi ? ixa1 : ixa0;
            float w = wzz * wyy * (xi ? wx : 1.f - wx);
            f32x2 w2 = {w, w};
            long vi = ((long)izz * GS + iyy) * GS + ixx;
            if constexpr (TA) {
              const uint4* gp = (const uint4*)(gridT + vi * NCH + 16 * half);
              uint4 g0 = gp[0], g1 = gp[1];
#define ACC_PAIR(u, i)                                                     \
  {                                                                        \
    f32x2 u2 = {__uint_as_float((u) << 16),                                \
                __uint_as_float((u) & 0xffff0000u)};                       \
    f2[i] = __builtin_elementwise_fma(u2, w2, f2[i]);                      \
  }
              ACC_PAIR(g0.x, 0) ACC_PAIR(g0.y, 1) ACC_PAIR(g0.z, 2) ACC_PAIR(g0.w, 3)
              ACC_PAIR(g1.x, 4) ACC_PAIR(g1.y, 5) ACC_PAIR(g1.z, 6) ACC_PAIR(g1.w, 7)
#undef ACC_PAIR
            } else {
#pragma unroll
              for (int i = 0; i < 8; ++i) {
                int c = 16 * half + 2 * i;
                f32x2 u2 = {gridF[(long)c * GV + vi], gridF[(long)(c + 1) * GV + vi]};
                f2[i] = __builtin_elementwise_fma(u2, w2, f2[i]);
              }
            }
          }
        }
      }
    }

    // ---- A0 fragment stores (6 aligned b128 per lane)
    {
      char* fbase = scr + (mtg * 3) * 1024;
      int ro = pmg * 16;
      uint4 s;
      // kt0: feats, qfrag 2h and 2h+1
      s.x = pkbf(f2[0].x, f2[0].y); s.y = pkbf(f2[1].x, f2[1].y);
      s.z = pkbf(f2[2].x, f2[2].y); s.w = pkbf(f2[3].x, f2[3].y);
      *(uint4*)(fbase + (2 * half) * 256 + ro) = s;
      s.x = pkbf(f2[4].x, f2[4].y); s.y = pkbf(f2[5].x, f2[5].y);
      s.z = pkbf(f2[6].x, f2[6].y); s.w = pkbf(f2[7].x, f2[7].y);
      *(uint4*)(fbase + (2 * half + 1) * 256 + ro) = s;
      // kt1: posenc dims 0..31
      s.x = pd[0]; s.y = pd[1]; s.z = pd[2]; s.w = pd[3];
      *(uint4*)(fbase + 1024 + (2 * half) * 256 + ro) = s;
      s.x = pd[4]; s.y = pd[5]; s.z = pd[6]; s.w = pd[7];
      *(uint4*)(fbase + 1024 + (2 * half + 1) * 256 + ro) = s;
      // kt2: posenc dims 32..35 + zero pad
      s.x = e0; s.y = e1; s.z = 0u; s.w = 0u;
      *(uint4*)(fbase + 2048 + (2 * half) * 256 + ro) = s;
      s.x = 0u; s.y = 0u; s.z = 0u; s.w = 0u;
      *(uint4*)(fbase + 2048 + (2 * half + 1) * 256 + ro) = s;
    }
    __builtin_amdgcn_wave_barrier();

    // prefetch next tile's coords (overlaps MFMA phases)
    if (tn < NTILES) {
      long p = (long)tn * TILE_PTS + pt;
      px = X[p * 3 + 0]; py = X[p * 3 + 1]; pz = X[p * 3 + 2];
    }

    // ---- layer 0: h0 = relu(A0 * W0^T + b0)
    bf16x8 a0[6];
#pragma unroll
    for (int mt = 0; mt < 2; ++mt)
#pragma unroll
      for (int kt = 0; kt < 3; ++kt)
        a0[mt * 3 + kt] = *(const bf16x8*)(scr + (mt * 3 + kt) * 1024 + lane * 16);
    __builtin_amdgcn_wave_barrier();
#pragma unroll
    for (int nt = 0; nt < 8; ++nt) {
      float bn = lb0[nt * 16 + ln];
      f32x4 cinit = {bn, bn, bn, bn};
      f32x4 acc[2];
      acc[0] = cinit; acc[1] = cinit;
#pragma unroll
      for (int kt = 0; kt < 3; ++kt) {
        bf16x8 bfr = *(const bf16x8*)(smem + (kt * 8 + nt) * 1024 + lane * 16);
#pragma unroll
        for (int mt = 0; mt < 2; ++mt)
          acc[mt] = __builtin_amdgcn_mfma_f32_16x16x32_bf16(a0[mt * 3 + kt], bfr, acc[mt], 0, 0, 0);
      }
      // C-layout (col n=ln, row m=q*4+r) -> h0 A-frag-linear (frags mt*4+kt1)
      int n = nt * 16 + ln;
      int kt1 = n >> 5, j = n & 7, sub = (n >> 3) & 3;
#pragma unroll
      for (int mt = 0; mt < 2; ++mt)
#pragma unroll
        for (int r = 0; r < 4; ++r) {
          float h = fmaxf(acc[mt][r], 0.f);
          *(unsigned short*)(scr + (mt * 4 + kt1) * 1024 + (sub * 16 + q * 4 + r) * 16 + j * 2) =
              (unsigned short)f2bf(h);
        }
    }
    __builtin_amdgcn_wave_barrier();

    // ---- layer 1 + fused layer 2
    bf16x8 a1[8];
#pragma unroll
    for (int mt = 0; mt < 2; ++mt)
#pragma unroll
      for (int kt = 0; kt < 4; ++kt)
        a1[mt * 4 + kt] = *(const bf16x8*)(scr + (mt * 4 + kt) * 1024 + lane * 16);
    __builtin_amdgcn_wave_barrier();
    float y[8];
#pragma unroll
    for (int i = 0; i < 8; ++i) y[i] = 0.f;
#pragma unroll
    for (int nt = 0; nt < 8; ++nt) {
      float bn = lb1[nt * 16 + ln];
      float w2n = lw2[nt * 16 + ln];
      f32x4 cinit = {bn, bn, bn, bn};
      f32x4 acc[2];
      acc[0] = cinit; acc[1] = cinit;
#pragma unroll
      for (int kt = 0; kt < 4; ++kt) {
        bf16x8 bfr = *(const bf16x8*)(smem + 24576 + (kt * 8 + nt) * 1024 + lane * 16);
#pragma unroll
        for (int mt = 0; mt < 2; ++mt)
          acc[mt] = __builtin_amdgcn_mfma_f32_16x16x32_bf16(a1[mt * 4 + kt], bfr, acc[mt], 0, 0, 0);
      }
#pragma unroll
      for (int mt = 0; mt < 2; ++mt)
#pragma unroll
        for (int r = 0; r < 4; ++r)
          y[mt * 4 + r] += w2n * fmaxf(acc[mt][r], 0.f);
    }
#pragma unroll
    for (int i = 0; i < 8; ++i) {
      float v = y[i];
      v += __shfl_xor(v, 1);
      v += __shfl_xor(v, 2);
      v += __shfl_xor(v, 4);
      v += __shfl_xor(v, 8);
      y[i] = v;
    }
    if (ln == 0) {
#pragma unroll
      for (int mt = 0; mt < 2; ++mt)
#pragma unroll
        for (int r = 0; r < 4; ++r)
          out[p0 + mt * 16 + q * 4 + r] = (y[mt * 4 + r] + b2s) * 2.f - 1.f;
    }
    t = tn;
  }
}

extern "C" void kernel_launch(void* const* d_in, const int* in_sizes, int n_in,
                              void* d_out, int out_size, void* d_ws, size_t ws_size,
                              hipStream_t stream) {
  const float* X  = (const float*)d_in[0];
  const float* G  = (const float*)d_in[1];
  const float* W0 = (const float*)d_in[2];
  const float* B0 = (const float*)d_in[3];
  const float* W1 = (const float*)d_in[4];
  const float* B1 = (const float*)d_in[5];
  const float* W2 = (const float*)d_in[6];
  const float* B2 = (const float*)d_in[7];
  float* out = (float*)d_out;

  const size_t needT = (size_t)GV * NCH * 2;  // 56.6 MB transposed bf16 grid
  const size_t shmem = 157184;

  if (ws_size >= needT) {
    k_prep_grid<<<GV / 256, 256, 0, stream>>>(G, (unsigned int*)d_ws);
    k_fvsrn<true><<<NBLK, NTHR, shmem, stream>>>(
        X, G, (const unsigned short*)d_ws, W0, B0, W1, B1, W2, B2, out);
  } else {
    k_fvsrn<false><<<NBLK, NTHR, shmem, stream>>>(
        X, G, (const unsigned short*)nullptr, W0, B0, W1, B1, W2, B2, out);
  }
}